// Round 3
// baseline (124.378 us; speedup 1.0000x reference)
//
#include <hip/hip_runtime.h>

typedef unsigned short ushort_t;
typedef __attribute__((ext_vector_type(8))) short bfrag;
typedef __attribute__((ext_vector_type(4))) float f4;

// B=4, D=256, H=W=64, num_levels=4, radius=4
#define NB 4
#define ND 256
#define NH 64
#define NW 64
#define NQ (NH * NW)            // 4096 queries per batch
#define MPAD 5504               // 43 * 128 rows of pooled-f2 features
#define NLVL 4
#define NCH (NLVL * 81)

__device__ __forceinline__ float bf2f(ushort_t u) {
    return __uint_as_float(((unsigned)u) << 16);
}
__device__ __forceinline__ ushort_t f2bf(float f) {
    unsigned u = __float_as_uint(f);
    unsigned r = (u + 0x7fffu + ((u >> 16) & 1u)) >> 16;
    return (ushort_t)r;
}

__device__ __forceinline__ void gload_lds16(const void* g, void* l) {
    __builtin_amdgcn_global_load_lds(
        (const __attribute__((address_space(1))) unsigned int*)g,
        (__attribute__((address_space(3))) unsigned int*)l, 16, 0, 0);
}

// ---------- kernel 1: fused transpose [b][256][4096] f32 -> [b][n][256] bf16 ----------
// z < NB: fmap1 -> Abf (scaled by 1/16, exact exponent shift); z >= NB: fmap2 -> Ball
__global__ __launch_bounds__(256) void transpose_cvt(
    const float* __restrict__ f1, const float* __restrict__ f2,
    ushort_t* __restrict__ Abf, ushort_t* __restrict__ Ball)
{
    __shared__ float tile[64][65];
    const int tid = threadIdx.x;
    const int z = blockIdx.z;
    const int b = z & 3;
    const bool isA = (z < NB);
    const float* ib = (isA ? f1 : f2) + (size_t)b * ND * NQ;
    ushort_t* ob = isA ? (Abf + (size_t)b * NQ * ND) : (Ball + (size_t)b * MPAD * ND);
    const float scale = isA ? 0.0625f : 1.0f;
    const int n0 = blockIdx.x * 64, d0 = blockIdx.y * 64;
    const int nl = tid & 63, dg = tid >> 6;
#pragma unroll
    for (int i = 0; i < 16; i++) {
        int dl = dg + i * 4;
        tile[dl][nl] = ib[(size_t)(d0 + dl) * NQ + n0 + nl];
    }
    __syncthreads();
    const int dl = tid & 63, ng = tid >> 6;
#pragma unroll
    for (int i = 0; i < 16; i++) {
        int nn = ng + i * 4;
        ob[(size_t)(n0 + nn) * ND + d0 + dl] = f2bf(tile[dl][nn] * scale);
    }
}

// ---------- kernel 2: all pyramid levels pooled directly from level-0 features ----------
// one block per (b, pooled-row); threads = d
__global__ __launch_bounds__(256) void pool_all(ushort_t* __restrict__ Ball)
{
    const int d = threadIdx.x;
    int rest = blockIdx.x;               // 0 .. NB*1344-1
    const int b = rest / 1344;
    int ml = rest - b * 1344;
    int lvl, m, outoff;
    if (ml < 1024)      { lvl = 1; m = ml;        outoff = 4096; }
    else if (ml < 1280) { lvl = 2; m = ml - 1024; outoff = 5120; }
    else                { lvl = 3; m = ml - 1280; outoff = 5376; }
    const int logW = 6 - lvl;
    const int Wl = 1 << logW;
    const int f = 1 << lvl;
    const int y = m >> logW, x = m & (Wl - 1);
    const ushort_t* src = Ball + (size_t)b * MPAD * ND;
    float s = 0.f;
    for (int iy = 0; iy < f; iy++)
        for (int ix = 0; ix < f; ix++)
            s += bf2f(src[(size_t)((y * f + iy) * 64 + x * f + ix) * ND + d]);
    Ball[((size_t)b * MPAD + outoff + m) * ND + d] = f2bf(s / (float)(f * f));
}

// ---------- kernel 2b: per-(batch,level,query) integer window base table ----------
__global__ void make_tbl(const float* __restrict__ coords, int* __restrict__ tbl)
{
    int t = blockIdx.x * 256 + threadIdx.x;     // b*4096 + q
    int b = t >> 12, q = t & 4095;
    float cx = coords[((size_t)b * 2 + 0) * NQ + q];
    float cy = coords[((size_t)b * 2 + 1) * NQ + q];
#pragma unroll
    for (int lvl = 0; lvl < 4; lvl++) {
        float s = 1.0f / (float)(1 << lvl);
        int x0 = (int)floorf(cx * s);
        int y0 = (int)floorf(cy * s);
        tbl[((b * 4 + lvl) << 12) + q] = (x0 & 0xffff) | (y0 << 16);
    }
}

// ---------- kernel 3: dbuf bf16 MFMA GEMM, LDS-swizzled, compacted epilogue ----------
// grid.x = 5504 = 4 batches * 32 n-tiles * 43 m-tiles, XCD-swizzled
__global__ __launch_bounds__(256) void gemm_corr(
    const ushort_t* __restrict__ A,     // [NB][4096][256] bf16 (pre-scaled by 1/16)
    const ushort_t* __restrict__ Bm,    // [NB][MPAD][256] bf16
    ushort_t* __restrict__ compact,     // [NB][4096][400] bf16
    const int* __restrict__ tbl)        // [NB][4][4096] packed (x0,y0)
{
    __shared__ ushort_t As[2][128 * 32];
    __shared__ ushort_t Bs[2][128 * 32];

    // bijective XCD-chunk swizzle: 5504 = 8 * 688
    const int l   = blockIdx.x;
    const int wg  = (l & 7) * 688 + (l >> 3);
    const int z   = wg / 1376;
    const int rem = wg - z * 1376;
    const int by  = rem / 43;
    const int bxt = rem - by * 43;

    int lvl, lbase, mbase;
    if (bxt < 32)      { lvl = 0; lbase = bxt * 128;        mbase = lbase; }
    else if (bxt < 40) { lvl = 1; lbase = (bxt - 32) * 128; mbase = 4096 + lbase; }
    else if (bxt < 42) { lvl = 2; lbase = (bxt - 40) * 128; mbase = 5120 + lbase; }
    else               { lvl = 3; lbase = 0;                mbase = 5376; }

    const int tid  = threadIdx.x;
    const int lane = tid & 63;
    const int wv   = tid >> 6;
    const int wr   = wv >> 1, wc = wv & 1;

    const ushort_t* Ab = A  + ((size_t)z * NQ   + (size_t)by * 128) * ND;
    const ushort_t* Bb = Bm + ((size_t)z * MPAD + (size_t)mbase) * ND;

    f4 acc[4][4] = {};
    const int r0 = tid >> 2;          // staged row within 64-row half
    const int c8 = tid & 3;           // dest 16B slot within the 32-wide K slice
    const int s0 = (r0 >> 1) & 3;     // XOR swizzle key (same for row r0 and 64+r0)

    // rule #21: linear LDS dest + inverse-swizzled global SOURCE + swizzled READ
#define STAGE(buf, kk) {                                                                  \
    gload_lds16(Ab + (size_t)r0 * ND + (kk) + (c8 ^ s0) * 8,        &As[buf][tid * 8]);   \
    gload_lds16(Ab + (size_t)(64 + r0) * ND + (kk) + (c8 ^ s0) * 8, &As[buf][(256+tid)*8]);\
    gload_lds16(Bb + (size_t)r0 * ND + (kk) + (c8 ^ s0) * 8,        &Bs[buf][tid * 8]);   \
    gload_lds16(Bb + (size_t)(64 + r0) * ND + (kk) + (c8 ^ s0) * 8, &Bs[buf][(256+tid)*8]);}

    const int sl = ((lane & 15) >> 1) & 3;       // read-side swizzle key
    const int kch = ((lane >> 4) ^ sl) * 8;      // swizzled 8-elem slot

    STAGE(0, 0);
#pragma unroll
    for (int t = 0; t < 8; ++t) {
        const int cur = t & 1;
        if (t < 7) {
            STAGE(cur ^ 1, (t + 1) * 32);
            asm volatile("s_waitcnt vmcnt(4)" ::: "memory");
        } else {
            asm volatile("s_waitcnt vmcnt(0)" ::: "memory");
        }
        __builtin_amdgcn_s_barrier();       // buf[cur] fully staged by all waves
        asm volatile("" ::: "memory");

        bfrag a[4], bb[4];
#pragma unroll
        for (int mi = 0; mi < 4; mi++)
            a[mi] = *reinterpret_cast<const bfrag*>(
                &As[cur][(wr * 64 + mi * 16 + (lane & 15)) * 32 + kch]);
#pragma unroll
        for (int ni = 0; ni < 4; ni++)
            bb[ni] = *reinterpret_cast<const bfrag*>(
                &Bs[cur][(wc * 64 + ni * 16 + (lane & 15)) * 32 + kch]);
#pragma unroll
        for (int mi = 0; mi < 4; mi++)
#pragma unroll
            for (int ni = 0; ni < 4; ni++)
                acc[mi][ni] = __builtin_amdgcn_mfma_f32_16x16x32_bf16(
                    a[mi], bb[ni], acc[mi][ni], 0, 0, 0);

        __builtin_amdgcn_s_barrier();       // all waves done reading buf[cur]
        asm volatile("" ::: "memory");
    }
#undef STAGE

    // ---- compacted epilogue: keep only dots inside some query's 10x10 window ----
    const int row_base    = by * 128 + wr * 64 + ((lane >> 4) << 2);
    const int col_in_lvl0 = lbase + wc * 64 + (lane & 15);
    const unsigned Wm1  = (64u >> lvl) - 1u;
    const int logW      = 6 - lvl;
    const int* tb       = tbl + (((size_t)z * 4 + lvl) << 12);
    ushort_t* cmp       = compact + (size_t)z * NQ * 400 + lvl * 100;

    int ux[4], vy[4];
#pragma unroll
    for (int ni = 0; ni < 4; ni++) {
        int cl = col_in_lvl0 + ni * 16;
        ux[ni] = (int)(cl & Wm1) + 4;    // u = ux - x0
        vy[ni] = (cl >> logW) + 4;       // v = vy - y0
    }

#pragma unroll
    for (int mi = 0; mi < 4; mi++)
#pragma unroll
        for (int j = 0; j < 4; j++) {
            int q  = row_base + mi * 16 + j;
            int xy = tb[q];
            int x0 = xy & 0xffff, y0 = xy >> 16;
#pragma unroll
            for (int ni = 0; ni < 4; ni++) {
                unsigned u = (unsigned)(ux[ni] - x0);
                unsigned v = (unsigned)(vy[ni] - y0);
                if (u < 10u && v < 10u)
                    cmp[(size_t)q * 400 + v * 10 + u] = f2bf(acc[mi][ni][j]);
            }
        }
}

// ---------- kernel 4: bilinear sampling from the compact window buffer ----------
__global__ __launch_bounds__(256) void sample_kernel(
    const ushort_t* __restrict__ compact,  // [NB][4096][400] bf16
    const float* __restrict__ coords,
    float* __restrict__ out)               // [NB][324][64][64] f32
{
    __shared__ int   X0s[16], Y0s[16];
    __shared__ float wxs[16], wys[16];
    __shared__ float Dl[16 * 101];
    const int tid = threadIdx.x;
    const int g   = blockIdx.x;
    const int lvl = blockIdx.y;
    const int b   = blockIdx.z;
    const int Wl  = NW >> lvl;

    if (tid < 16) {
        int q = g * 16 + tid;
        float cx = coords[(size_t)(b * 2 + 0) * NQ + q];
        float cy = coords[(size_t)(b * 2 + 1) * NQ + q];
        float s = 1.0f / (float)(1 << lvl);
        float xl = cx * s, yl = cy * s;
        float fx = floorf(xl), fy = floorf(yl);
        X0s[tid] = (int)fx;
        Y0s[tid] = (int)fy;
        wxs[tid] = xl - fx;
        wys[tid] = yl - fy;
    }
    __syncthreads();

#pragma unroll
    for (int r = 0; r < 7; r++) {
        int e = r * 256 + tid;
        if (e < 16 * 100) {
            int qi = e / 100;
            int el = e - qi * 100;
            int v = el / 10;
            int u = el - v * 10;
            int xx = X0s[qi] - 4 + u;
            int yy = Y0s[qi] - 4 + v;
            float val = 0.f;
            if ((unsigned)xx < (unsigned)Wl && (unsigned)yy < (unsigned)Wl)
                val = bf2f(compact[((size_t)b * NQ + g * 16 + qi) * 400
                                   + lvl * 100 + el]);
            Dl[qi * 101 + el] = val;
        }
    }
    __syncthreads();

#pragma unroll
    for (int r = 0; r < 6; r++) {
        int e = r * 256 + tid;
        if (e < 16 * 81) {
            int qi = e & 15;
            int c = e >> 4;
            int i = c / 9;            // x-offset grid index
            int j = c - i * 9;        // y-offset grid index
            float wx = wxs[qi], wy = wys[qi];
            const float* dq = &Dl[qi * 101];
            float d00 = dq[j * 10 + i];
            float d10 = dq[j * 10 + i + 1];
            float d01 = dq[(j + 1) * 10 + i];
            float d11 = dq[(j + 1) * 10 + i + 1];
            float vx0 = d00 + wx * (d10 - d00);
            float vx1 = d01 + wx * (d11 - d01);
            float val = vx0 + wy * (vx1 - vx0);
            out[((size_t)b * NCH + lvl * 81 + c) * NQ + g * 16 + qi] = val;
        }
    }
}

extern "C" void kernel_launch(void* const* d_in, const int* in_sizes, int n_in,
                              void* d_out, int out_size, void* d_ws, size_t ws_size,
                              hipStream_t stream)
{
    const float* fmap1  = (const float*)d_in[0];
    const float* fmap2  = (const float*)d_in[1];
    const float* coords = (const float*)d_in[2];
    float* out = (float*)d_out;

    char* ws = (char*)d_ws;
    const size_t A_BYTES   = (size_t)NB * NQ * ND * 2;     //  8.4 MB
    const size_t B_BYTES   = (size_t)NB * MPAD * ND * 2;   // 11.3 MB
    const size_t CMP_BYTES = (size_t)NB * NQ * 400 * 2;    // 13.1 MB
    ushort_t* Abf  = (ushort_t*)ws;
    ushort_t* Ball = (ushort_t*)(ws + A_BYTES);
    ushort_t* cmp  = (ushort_t*)(ws + A_BYTES + B_BYTES);
    int*      tbl  = (int*)(ws + A_BYTES + B_BYTES + CMP_BYTES);

    transpose_cvt<<<dim3(64, 4, 2 * NB), 256, 0, stream>>>(fmap1, fmap2, Abf, Ball);

    pool_all<<<NB * 1344, 256, 0, stream>>>(Ball);

    make_tbl<<<(NB * NQ) / 256, 256, 0, stream>>>(coords, tbl);

    gemm_corr<<<dim3(43 * 32 * NB), 256, 0, stream>>>(Abf, Ball, cmp, tbl);

    sample_kernel<<<dim3(256, NLVL, NB), 256, 0, stream>>>(cmp, coords, out);
}

// Round 4
// 104.930 us; speedup vs baseline: 1.1853x; 1.1853x over previous
//
#include <hip/hip_runtime.h>

typedef unsigned short ushort_t;
typedef __attribute__((ext_vector_type(8))) short bfrag;
typedef __attribute__((ext_vector_type(4))) float f4;

// B=4, D=256, H=W=64, num_levels=4, radius=4
#define NB 4
#define ND 256
#define NH 64
#define NW 64
#define NQ (NH * NW)            // 4096 queries per batch
#define MPAD 5504               // 43 * 128 rows of pooled-f2 features
#define NLVL 4
#define NCH (NLVL * 81)

__device__ __forceinline__ float bf2f(ushort_t u) {
    return __uint_as_float(((unsigned)u) << 16);
}
__device__ __forceinline__ ushort_t f2bf(float f) {
    unsigned u = __float_as_uint(f);
    unsigned r = (u + 0x7fffu + ((u >> 16) & 1u)) >> 16;
    return (ushort_t)r;
}

__device__ __forceinline__ void gload_lds16(const void* g, void* l) {
    __builtin_amdgcn_global_load_lds(
        (const __attribute__((address_space(1))) unsigned int*)g,
        (__attribute__((address_space(3))) unsigned int*)l, 16, 0, 0);
}

// ---------- kernel 1: transpose [b][256][4096] f32 -> [b][n][256] bf16 (opt. scale) ----------
__global__ __launch_bounds__(256) void transpose_cvt(
    const float* __restrict__ in, ushort_t* __restrict__ outp,
    size_t in_bstride, size_t out_bstride, float scale)
{
    __shared__ float tile[64][65];
    const int tid = threadIdx.x;
    const int n0 = blockIdx.x * 64, d0 = blockIdx.y * 64, b = blockIdx.z;
    const float* ib = in + (size_t)b * in_bstride;
    ushort_t* ob = outp + (size_t)b * out_bstride;
    const int nl = tid & 63, dg = tid >> 6;
#pragma unroll
    for (int i = 0; i < 16; i++) {
        int dl = dg + i * 4;
        tile[dl][nl] = ib[(size_t)(d0 + dl) * NQ + n0 + nl];
    }
    __syncthreads();
    const int dl = tid & 63, ng = tid >> 6;
#pragma unroll
    for (int i = 0; i < 16; i++) {
        int nn = ng + i * 4;
        ob[(size_t)(n0 + nn) * ND + d0 + dl] = f2bf(tile[dl][nn] * scale);
    }
}

// ---------- kernel 2: avg-pool 2x2 in [m][d] bf16 layout (cascade) ----------
__global__ void pool_kernel(ushort_t* __restrict__ Ball, int Wlo, int in_off, int out_off)
{
    int t = blockIdx.x * 256 + threadIdx.x;
    int d = t & 255;
    int rest = t >> 8;
    int Nl = Wlo * Wlo;
    int m = rest % Nl;
    int b = rest / Nl;
    if (b >= NB) return;
    int y = m / Wlo, x = m - y * Wlo;
    int Wi = Wlo * 2;
    const ushort_t* src = Ball + (size_t)b * MPAD * ND;
    float s = 0.f;
#pragma unroll
    for (int iy = 0; iy < 2; iy++)
#pragma unroll
        for (int ix = 0; ix < 2; ix++)
            s += bf2f(src[(size_t)(in_off + (2 * y + iy) * Wi + (2 * x + ix)) * ND + d]);
    Ball[(size_t)b * MPAD * ND + (size_t)(out_off + m) * ND + d] = f2bf(s * 0.25f);
}

// ---------- kernel 2b: per-(batch,level,query) integer window base table ----------
__global__ void make_tbl(const float* __restrict__ coords, int* __restrict__ tbl)
{
    int t = blockIdx.x * 256 + threadIdx.x;     // b*4096 + q
    int b = t >> 12, q = t & 4095;
    float cx = coords[((size_t)b * 2 + 0) * NQ + q];
    float cy = coords[((size_t)b * 2 + 1) * NQ + q];
#pragma unroll
    for (int lvl = 0; lvl < 4; lvl++) {
        float s = 1.0f / (float)(1 << lvl);
        int x0 = (int)floorf(cx * s);
        int y0 = (int)floorf(cy * s);
        tbl[((b * 4 + lvl) << 12) + q] = (x0 & 0xffff) | (y0 << 16);
    }
}

// ---------- kernel 3: 3-buffer (prefetch-distance-2) bf16 MFMA GEMM ----------
// grid.x = 5504 = 4 batches * 32 n-tiles * 43 m-tiles, XCD-swizzled
__global__ __launch_bounds__(256) void gemm_corr(
    const ushort_t* __restrict__ A,     // [NB][4096][256] bf16 (pre-scaled by 1/16)
    const ushort_t* __restrict__ Bm,    // [NB][MPAD][256] bf16
    ushort_t* __restrict__ compact,     // [NB][4096][400] bf16
    const int* __restrict__ tbl)        // [NB][4][4096] packed (x0,y0)
{
    __shared__ ushort_t As[3][128 * 32];
    __shared__ ushort_t Bs[3][128 * 32];

    // bijective XCD-chunk swizzle: 5504 = 8 * 688
    const int l   = blockIdx.x;
    const int wg  = (l & 7) * 688 + (l >> 3);
    const int z   = wg / 1376;
    const int rem = wg - z * 1376;
    const int by  = rem / 43;
    const int bxt = rem - by * 43;

    int lvl, lbase, mbase;
    if (bxt < 32)      { lvl = 0; lbase = bxt * 128;        mbase = lbase; }
    else if (bxt < 40) { lvl = 1; lbase = (bxt - 32) * 128; mbase = 4096 + lbase; }
    else if (bxt < 42) { lvl = 2; lbase = (bxt - 40) * 128; mbase = 5120 + lbase; }
    else               { lvl = 3; lbase = 0;                mbase = 5376; }

    const int tid  = threadIdx.x;
    const int lane = tid & 63;
    const int wv   = tid >> 6;
    const int wr   = wv >> 1, wc = wv & 1;

    const ushort_t* Ab = A  + ((size_t)z * NQ   + (size_t)by * 128) * ND;
    const ushort_t* Bb = Bm + ((size_t)z * MPAD + (size_t)mbase) * ND;

    f4 acc[4][4] = {};
    const int r0 = tid >> 2;          // staged row within 64-row half
    const int c8 = tid & 3;           // dest 16B slot within the 32-wide K slice
    const int s0 = (r0 >> 1) & 3;     // XOR swizzle key (same for row r0 and 64+r0)

    // rule #21: linear LDS dest + inverse-swizzled global SOURCE + swizzled READ
#define STAGE(buf, kk) {                                                                  \
    gload_lds16(Ab + (size_t)r0 * ND + (kk) + (c8 ^ s0) * 8,        &As[buf][tid * 8]);   \
    gload_lds16(Ab + (size_t)(64 + r0) * ND + (kk) + (c8 ^ s0) * 8, &As[buf][(256+tid)*8]);\
    gload_lds16(Bb + (size_t)r0 * ND + (kk) + (c8 ^ s0) * 8,        &Bs[buf][tid * 8]);   \
    gload_lds16(Bb + (size_t)(64 + r0) * ND + (kk) + (c8 ^ s0) * 8, &Bs[buf][(256+tid)*8]);}

    const int sl = ((lane & 15) >> 1) & 3;       // read-side swizzle key
    const int kch = ((lane >> 4) ^ sl) * 8;      // swizzled 8-elem slot

    STAGE(0, 0);
    STAGE(1, 32);
    STAGE(2, 64);

#pragma unroll
    for (int t = 0; t < 8; ++t) {
        const int cur = t % 3;
        // needed slot's loads are 2 K-steps old -> near-zero stall
        if (t < 6)       { asm volatile("s_waitcnt vmcnt(8)" ::: "memory"); }
        else if (t == 6) { asm volatile("s_waitcnt vmcnt(4)" ::: "memory"); }
        else             { asm volatile("s_waitcnt vmcnt(0)" ::: "memory"); }
        __builtin_amdgcn_s_barrier();        // #1: slot `cur` fully staged
        asm volatile("" ::: "memory");

        bfrag a[4], bb[4];
#pragma unroll
        for (int mi = 0; mi < 4; mi++)
            a[mi] = *reinterpret_cast<const bfrag*>(
                &As[cur][(wr * 64 + mi * 16 + (lane & 15)) * 32 + kch]);
#pragma unroll
        for (int ni = 0; ni < 4; ni++)
            bb[ni] = *reinterpret_cast<const bfrag*>(
                &Bs[cur][(wc * 64 + ni * 16 + (lane & 15)) * 32 + kch]);

        if (t < 5) {
            __builtin_amdgcn_sched_barrier(0);                    // pin ds_reads above
            asm volatile("s_waitcnt lgkmcnt(0)" ::: "memory");    // my reads complete
            __builtin_amdgcn_s_barrier();     // #2: all waves done reading slot `cur`
            asm volatile("" ::: "memory");
            STAGE(cur, (t + 3) * 32);         // overwrite slot `cur` with K-step t+3
        }

#pragma unroll
        for (int mi = 0; mi < 4; mi++)
#pragma unroll
            for (int ni = 0; ni < 4; ni++)
                acc[mi][ni] = __builtin_amdgcn_mfma_f32_16x16x32_bf16(
                    a[mi], bb[ni], acc[mi][ni], 0, 0, 0);
    }
#undef STAGE

    // ---- compacted epilogue: keep only dots inside some query's 10x10 window ----
    const int row_base    = by * 128 + wr * 64 + ((lane >> 4) << 2);
    const int col_in_lvl0 = lbase + wc * 64 + (lane & 15);
    const unsigned Wm1  = (64u >> lvl) - 1u;
    const int logW      = 6 - lvl;
    const int* tb       = tbl + (((size_t)z * 4 + lvl) << 12);
    ushort_t* cmp       = compact + (size_t)z * NQ * 400 + lvl * 100;

    int ux[4], vy[4];
#pragma unroll
    for (int ni = 0; ni < 4; ni++) {
        int cl = col_in_lvl0 + ni * 16;
        ux[ni] = (int)(cl & Wm1) + 4;    // u = ux - x0
        vy[ni] = (cl >> logW) + 4;       // v = vy - y0
    }

#pragma unroll
    for (int mi = 0; mi < 4; mi++)
#pragma unroll
        for (int j = 0; j < 4; j++) {
            int q  = row_base + mi * 16 + j;
            int xy = tb[q];
            int x0 = xy & 0xffff, y0 = xy >> 16;
#pragma unroll
            for (int ni = 0; ni < 4; ni++) {
                unsigned u = (unsigned)(ux[ni] - x0);
                unsigned v = (unsigned)(vy[ni] - y0);
                if (u < 10u && v < 10u)
                    cmp[(size_t)q * 400 + v * 10 + u] = f2bf(acc[mi][ni][j]);
            }
        }
}

// ---------- kernel 4: bilinear sampling from the compact window buffer ----------
__global__ __launch_bounds__(256) void sample_kernel(
    const ushort_t* __restrict__ compact,  // [NB][4096][400] bf16
    const float* __restrict__ coords,
    float* __restrict__ out)               // [NB][324][64][64] f32
{
    __shared__ int   X0s[16], Y0s[16];
    __shared__ float wxs[16], wys[16];
    __shared__ float Dl[16 * 101];
    const int tid = threadIdx.x;
    const int g   = blockIdx.x;
    const int lvl = blockIdx.y;
    const int b   = blockIdx.z;
    const int Wl  = NW >> lvl;

    if (tid < 16) {
        int q = g * 16 + tid;
        float cx = coords[(size_t)(b * 2 + 0) * NQ + q];
        float cy = coords[(size_t)(b * 2 + 1) * NQ + q];
        float s = 1.0f / (float)(1 << lvl);
        float xl = cx * s, yl = cy * s;
        float fx = floorf(xl), fy = floorf(yl);
        X0s[tid] = (int)fx;
        Y0s[tid] = (int)fy;
        wxs[tid] = xl - fx;
        wys[tid] = yl - fy;
    }
    __syncthreads();

#pragma unroll
    for (int r = 0; r < 7; r++) {
        int e = r * 256 + tid;
        if (e < 16 * 100) {
            int qi = e / 100;
            int el = e - qi * 100;
            int v = el / 10;
            int u = el - v * 10;
            int xx = X0s[qi] - 4 + u;
            int yy = Y0s[qi] - 4 + v;
            float val = 0.f;
            if ((unsigned)xx < (unsigned)Wl && (unsigned)yy < (unsigned)Wl)
                val = bf2f(compact[((size_t)b * NQ + g * 16 + qi) * 400
                                   + lvl * 100 + el]);
            Dl[qi * 101 + el] = val;
        }
    }
    __syncthreads();

#pragma unroll
    for (int r = 0; r < 6; r++) {
        int e = r * 256 + tid;
        if (e < 16 * 81) {
            int qi = e & 15;
            int c = e >> 4;
            int i = c / 9;            // x-offset grid index
            int j = c - i * 9;        // y-offset grid index
            float wx = wxs[qi], wy = wys[qi];
            const float* dq = &Dl[qi * 101];
            float d00 = dq[j * 10 + i];
            float d10 = dq[j * 10 + i + 1];
            float d01 = dq[(j + 1) * 10 + i];
            float d11 = dq[(j + 1) * 10 + i + 1];
            float vx0 = d00 + wx * (d10 - d00);
            float vx1 = d01 + wx * (d11 - d01);
            float val = vx0 + wy * (vx1 - vx0);
            out[((size_t)b * NCH + lvl * 81 + c) * NQ + g * 16 + qi] = val;
        }
    }
}

extern "C" void kernel_launch(void* const* d_in, const int* in_sizes, int n_in,
                              void* d_out, int out_size, void* d_ws, size_t ws_size,
                              hipStream_t stream)
{
    const float* fmap1  = (const float*)d_in[0];
    const float* fmap2  = (const float*)d_in[1];
    const float* coords = (const float*)d_in[2];
    float* out = (float*)d_out;

    char* ws = (char*)d_ws;
    const size_t A_BYTES   = (size_t)NB * NQ * ND * 2;     //  8.4 MB
    const size_t B_BYTES   = (size_t)NB * MPAD * ND * 2;   // 11.3 MB
    const size_t CMP_BYTES = (size_t)NB * NQ * 400 * 2;    // 13.1 MB
    ushort_t* Abf  = (ushort_t*)ws;
    ushort_t* Ball = (ushort_t*)(ws + A_BYTES);
    ushort_t* cmp  = (ushort_t*)(ws + A_BYTES + B_BYTES);
    int*      tbl  = (int*)(ws + A_BYTES + B_BYTES + CMP_BYTES);

    transpose_cvt<<<dim3(64, 4, NB), 256, 0, stream>>>(
        fmap1, Abf, (size_t)ND * NQ, (size_t)NQ * ND, 0.0625f);
    transpose_cvt<<<dim3(64, 4, NB), 256, 0, stream>>>(
        fmap2, Ball, (size_t)ND * NQ, (size_t)MPAD * ND, 1.0f);

    pool_kernel<<<(NB * 1024 * ND) / 256, 256, 0, stream>>>(Ball, 32, 0,    4096);
    pool_kernel<<<(NB * 256  * ND) / 256, 256, 0, stream>>>(Ball, 16, 4096, 5120);
    pool_kernel<<<(NB * 64   * ND) / 256, 256, 0, stream>>>(Ball, 8,  5120, 5376);

    make_tbl<<<(NB * NQ) / 256, 256, 0, stream>>>(coords, tbl);

    gemm_corr<<<dim3(43 * 32 * NB), 256, 0, stream>>>(Abf, Ball, cmp, tbl);

    sample_kernel<<<dim3(256, NLVL, NB), 256, 0, stream>>>(cmp, coords, out);
}